// Round 15
// baseline (123.194 us; speedup 1.0000x reference)
//
#include <hip/hip_runtime.h>
#include <hip/hip_bf16.h>
#include <hip/hip_fp16.h>

#define N_NODES 50000
#define N_EDGES 800000
#define HEADS 4
#define OUT_CH 32
#define FDIM (HEADS * OUT_CH)   // 128

typedef float vfloat4 __attribute__((ext_vector_type(4)));

// ============================================================================
// prep: A/B node dots + fp16 x-table + zero counters & scan finish flag
// ============================================================================

__global__ void prep_kernel(const float4* __restrict__ x4,
                            const float* __restrict__ w,
                            float* __restrict__ Af,
                            float* __restrict__ Bf,
                            ushort4* __restrict__ xh4,
                            int4* __restrict__ cnt_zero,
                            int n_cnt4,
                            int* __restrict__ done_ctr) {
    int gid = blockIdx.x * blockDim.x + threadIdx.x;

    if (gid < n_cnt4) cnt_zero[gid] = make_int4(0, 0, 0, 0);
    if (gid == 0) *done_ctr = 0;

    int node = gid >> 5;
    int t = threadIdx.x & 31;
    int h = t >> 3;
    int q8 = t & 7;

    float4 xv = x4[node * 32 + t];

    ushort4 u;
    u.x = __half_as_ushort(__float2half(xv.x));
    u.y = __half_as_ushort(__float2half(xv.y));
    u.z = __half_as_ushort(__float2half(xv.z));
    u.w = __half_as_ushort(__float2half(xv.w));
    xh4[node * 32 + t] = u;

    const float4* w4 = (const float4*)w;
    float4 wi = w4[q8];
    float4 wj = w4[8 + q8];
    float pa = xv.x * wi.x + xv.y * wi.y + xv.z * wi.z + xv.w * wi.w;
    float pb = xv.x * wj.x + xv.y * wj.y + xv.z * wj.z + xv.w * wj.w;
    #pragma unroll
    for (int m = 4; m >= 1; m >>= 1) {
        pa += __shfl_xor(pa, m);
        pb += __shfl_xor(pb, m);
    }
    if (q8 == 0) {
        Af[node * 4 + h] = pa;
        Bf[node * 4 + h] = pb;
    }
}

// ============================================================================
// hist + rank: counters one per 64B line (shift=4); 4 edges/thread
// ============================================================================

__global__ void hist_rank_kernel(const int* __restrict__ ei,
                                 int* __restrict__ cnt,
                                 ushort* __restrict__ rank,
                                 int n_edges, int shift) {
    int base = blockIdx.x * 1024 + threadIdx.x;
    #pragma unroll
    for (int u = 0; u < 4; ++u) {
        int e = base + u * 256;
        if (e < n_edges) {
            int i = ei[e];
            int r = atomicAdd(&cnt[i << shift], 1);
            rank[e] = (ushort)r;
        }
    }
}

// ============================================================================
// scan1 (+fused scan2 via last-arriving block):
//   - block-local exclusive scan of cnt -> offs (offs[n] valid)
//   - bsums[b] = block total
//   - LAST block to finish scans bsums -> bscan (exclusive)
// Consumers fold: global_off(i) = offs[i] + bscan[i>>8]
// ============================================================================

__global__ void scan1_kernel(const int* __restrict__ cnt, int* __restrict__ offs,
                             int* __restrict__ bsums, int* __restrict__ bscan,
                             int* __restrict__ done_ctr, int n, int shift) {
    __shared__ int lds[256];
    __shared__ bool is_last;
    int i = blockIdx.x * 256 + threadIdx.x;
    int v = (i < n) ? cnt[i << shift] : 0;
    lds[threadIdx.x] = v;
    __syncthreads();
    for (int d = 1; d < 256; d <<= 1) {
        int t = (threadIdx.x >= d) ? lds[threadIdx.x - d] : 0;
        __syncthreads();
        lds[threadIdx.x] += t;
        __syncthreads();
    }
    if (i <= n) offs[i] = lds[threadIdx.x] - v;   // i==n gets local-exclusive
    if (threadIdx.x == 255) bsums[blockIdx.x] = lds[255];

    // fence + finish-count; last block performs the bsums scan
    __threadfence();
    if (threadIdx.x == 0) {
        int prev = atomicAdd(done_ctr, 1);
        is_last = (prev == (int)gridDim.x - 1);
    }
    __syncthreads();
    if (is_last) {
        int nb = (int)gridDim.x;
        int bv = (threadIdx.x < nb) ? bsums[threadIdx.x] : 0;
        __syncthreads();
        lds[threadIdx.x] = bv;
        __syncthreads();
        for (int d = 1; d < 256; d <<= 1) {
            int t = (threadIdx.x >= d) ? lds[threadIdx.x - d] : 0;
            __syncthreads();
            lds[threadIdx.x] += t;
            __syncthreads();
        }
        bscan[threadIdx.x] = lds[threadIdx.x] - bv;
    }
}

// ============================================================================
// atomic-free record scatter: 4 edges/thread (782 blocks, ~3/CU)
// ============================================================================

__global__ void scatter_norank_kernel(const int* __restrict__ ei,
                                      const int* __restrict__ ej,
                                      const float* __restrict__ weights,
                                      const float4* __restrict__ A4,
                                      const float4* __restrict__ B4,
                                      const int* __restrict__ offs,
                                      const int* __restrict__ bscan,
                                      const ushort* __restrict__ rank,
                                      uint4* __restrict__ rec,
                                      int n_edges) {
    int base = blockIdx.x * (blockDim.x * 4) + threadIdx.x;
    #pragma unroll
    for (int u = 0; u < 4; ++u) {
        int e = base + u * 256;
        if (e >= n_edges) continue;
        int i = ei[e];
        int j = ej[e];
        float we = weights[e];
        int p = offs[i] + bscan[i >> 8] + (int)rank[e];
        float4 ai = A4[i];
        float4 bj = B4[j];
        float b0 = we / (1.0f + __expf(-(ai.x + bj.x)));
        float b1 = we / (1.0f + __expf(-(ai.y + bj.y)));
        float b2 = we / (1.0f + __expf(-(ai.z + bj.z)));
        float b3 = we / (1.0f + __expf(-(ai.w + bj.w)));
        uint w01 = (uint)__half_as_ushort(__float2half(b0)) |
                   ((uint)__half_as_ushort(__float2half(b1)) << 16);
        uint w23 = (uint)__half_as_ushort(__float2half(b2)) |
                   ((uint)__half_as_ushort(__float2half(b3)) << 16);
        uint4 r;
        r.x = (uint)j; r.y = w01; r.z = w23; r.w = 0u;
        rec[p] = r;
    }
}

// ============================================================================
// gather: 32 lanes/node, plain rec loads (line reuse), unroll 8, NT out store
// ============================================================================

__global__ void gather_rec_kernel(const ushort4* __restrict__ xh4,
                                  const int* __restrict__ offs,
                                  const int* __restrict__ bscan,
                                  const uint4* __restrict__ rec,
                                  float4* __restrict__ out4) {
    int gid = blockIdx.x * blockDim.x + threadIdx.x;
    int node = gid >> 5;
    int t = threadIdx.x & 31;
    int h = t >> 3;

    int start = offs[node] + bscan[node >> 8];
    int end = offs[node + 1] + bscan[(node + 1) >> 8];

    float4 acc = make_float4(0.f, 0.f, 0.f, 0.f);
    #pragma unroll 8
    for (int k = start; k < end; ++k) {
        uint4 r = rec[k];
        int j = (int)r.x;
        uint wrd = (h < 2) ? r.y : r.z;
        ushort hw = (h & 1) ? (ushort)(wrd >> 16) : (ushort)(wrd & 0xffffu);
        float beta = __half2float(__ushort_as_half(hw));
        ushort4 xv = xh4[j * 32 + t];
        acc.x += __half2float(__ushort_as_half(xv.x)) * beta;
        acc.y += __half2float(__ushort_as_half(xv.y)) * beta;
        acc.z += __half2float(__ushort_as_half(xv.z)) * beta;
        acc.w += __half2float(__ushort_as_half(xv.w)) * beta;
    }
    vfloat4 av; av.x = acc.x; av.y = acc.y; av.z = acc.z; av.w = acc.w;
    __builtin_nontemporal_store(av, (vfloat4*)&out4[node * 32 + t]);
}

// ============================================================================
// v0 ultimate fallback: atomic scatter
// ============================================================================

__global__ void node_dots_kernel(const float* __restrict__ x,
                                 const float* __restrict__ w,
                                 float* __restrict__ ab,
                                 int n_nodes) {
    int gid = blockIdx.x * blockDim.x + threadIdx.x;
    int node = gid >> 7;
    int t = threadIdx.x & 127;
    if (node >= n_nodes) return;
    int h = t >> 5;
    int c = t & 31;
    float xv = x[node * FDIM + t];
    float pa = xv * w[c];
    float pb = xv * w[OUT_CH + c];
    #pragma unroll
    for (int m = 16; m >= 1; m >>= 1) {
        pa += __shfl_xor(pa, m);
        pb += __shfl_xor(pb, m);
    }
    if (c == 0) {
        ab[node * 8 + h * 2 + 0] = pa;
        ab[node * 8 + h * 2 + 1] = pb;
    }
}

__global__ void edge_scatter_kernel(const float* __restrict__ x,
                                    const int* __restrict__ ei_arr,
                                    const int* __restrict__ ej_arr,
                                    const float* __restrict__ weights,
                                    const float* __restrict__ ab,
                                    float* __restrict__ out,
                                    int n_edges) {
    int gid = blockIdx.x * blockDim.x + threadIdx.x;
    int e = gid >> 7;
    int t = threadIdx.x & 127;
    if (e >= n_edges) return;
    int h = t >> 5;
    int i = ei_arr[e];
    int j = ej_arr[e];
    float alpha = ab[i * 8 + h * 2 + 0] + ab[j * 8 + h * 2 + 1];
    float beta = weights[e] / (1.0f + __expf(-alpha));
    atomicAdd(&out[i * FDIM + t], x[j * FDIM + t] * beta);
}

// ============================================================================

extern "C" void kernel_launch(void* const* d_in, const int* in_sizes, int n_in,
                              void* d_out, int out_size, void* d_ws, size_t ws_size,
                              hipStream_t stream) {
    const float* x       = (const float*)d_in[0];
    const int*   eidx    = (const int*)d_in[1];
    const float* weights = (const float*)d_in[2];
    const float* w       = (const float*)d_in[3];
    float* out = (float*)d_out;

    const int* ei_arr = eidx;
    const int* ej_arr = eidx + N_EDGES;

    const int NB = (N_NODES + 255) / 256;  // scan blocks (196)

    // ---- v15 workspace layout ----
    // xh: 12.8MB | A: .8MB | B: .8MB | rec: 12.8MB | rank: 1.6MB |
    // offs: (N+1)*4 | bsums: 1KB | bscan: 1KB | done: 4B | cnt_pad: N*64B
    {
        char* p = (char*)d_ws;
        ushort4* xh4  = (ushort4*)p;   p += (size_t)N_NODES * FDIM * 2;
        float*   Af   = (float*)p;     p += (size_t)N_NODES * 4 * 4;
        float*   Bf   = (float*)p;     p += (size_t)N_NODES * 4 * 4;
        uint4*   rec  = (uint4*)p;     p += (size_t)N_EDGES * 16;
        ushort*  rank = (ushort*)p;    p += (size_t)N_EDGES * 2;
        int*     offs = (int*)p;       p += (size_t)(N_NODES + 1) * 4;
        int*     bsums= (int*)p;       p += (size_t)256 * 4;
        int*     bscan= (int*)p;       p += (size_t)256 * 4;
        int*     done = (int*)p;       p += (size_t)16;   // finish counter
        int*     cnt  = (int*)p;       // strided counters at the end
        size_t base_need = (size_t)(p - (char*)d_ws);
        size_t need_pad  = base_need + (size_t)N_NODES * 16 * 4;  // shift=4
        size_t need_min  = base_need + (size_t)N_NODES * 4;       // shift=0

        int shift = -1;
        if (ws_size >= need_pad)      shift = 4;
        else if (ws_size >= need_min) shift = 0;

        if (shift >= 0) {
            int n_cnt4 = (N_NODES << shift) / 4;
            prep_kernel<<<(N_NODES * 32) / 256, 256, 0, stream>>>(
                (const float4*)x, w, Af, Bf, xh4, (int4*)cnt, n_cnt4, done);
            hist_rank_kernel<<<(N_EDGES + 1023) / 1024, 256, 0, stream>>>(
                ei_arr, cnt, rank, N_EDGES, shift);
            scan1_kernel<<<NB, 256, 0, stream>>>(
                cnt, offs, bsums, bscan, done, N_NODES, shift);
            scatter_norank_kernel<<<(N_EDGES + 1023) / 1024, 256, 0, stream>>>(
                ei_arr, ej_arr, weights, (const float4*)Af, (const float4*)Bf,
                offs, bscan, rank, rec, N_EDGES);
            gather_rec_kernel<<<(N_NODES * 32) / 256, 256, 0, stream>>>(
                xh4, offs, bscan, rec, (float4*)out);
            return;
        }
    }

    // ---- v0 atomic fallback ----
    {
        float* ab = (float*)d_ws;  // 1.6MB
        int grid = (N_NODES * FDIM + 255) / 256;
        node_dots_kernel<<<grid, 256, 0, stream>>>(x, w, ab, N_NODES);
        hipMemsetAsync(d_out, 0, (size_t)out_size * sizeof(float), stream);
        long long threads_total = (long long)N_EDGES * FDIM;
        long long g = (threads_total + 255) / 256;
        edge_scatter_kernel<<<(int)g, 256, 0, stream>>>(
            x, ei_arr, ej_arr, weights, ab, out, N_EDGES);
    }
}

// Round 16
// 118.290 us; speedup vs baseline: 1.0415x; 1.0415x over previous
//
#include <hip/hip_runtime.h>
#include <hip/hip_bf16.h>
#include <hip/hip_fp16.h>

#define N_NODES 50000
#define N_EDGES 800000
#define HEADS 4
#define OUT_CH 32
#define FDIM (HEADS * OUT_CH)   // 128

typedef float vfloat4 __attribute__((ext_vector_type(4)));

// ============================================================================
// prep: A/B node dots + fp16 x-table + zero counters & scan finish flag
// ============================================================================

__global__ void prep_kernel(const float4* __restrict__ x4,
                            const float* __restrict__ w,
                            float* __restrict__ Af,
                            float* __restrict__ Bf,
                            ushort4* __restrict__ xh4,
                            int4* __restrict__ cnt_zero,
                            int n_cnt4,
                            int* __restrict__ done_ctr) {
    int gid = blockIdx.x * blockDim.x + threadIdx.x;

    if (gid < n_cnt4) cnt_zero[gid] = make_int4(0, 0, 0, 0);
    if (gid == 0) *done_ctr = 0;

    int node = gid >> 5;
    int t = threadIdx.x & 31;
    int h = t >> 3;
    int q8 = t & 7;

    float4 xv = x4[node * 32 + t];

    ushort4 u;
    u.x = __half_as_ushort(__float2half(xv.x));
    u.y = __half_as_ushort(__float2half(xv.y));
    u.z = __half_as_ushort(__float2half(xv.z));
    u.w = __half_as_ushort(__float2half(xv.w));
    xh4[node * 32 + t] = u;

    const float4* w4 = (const float4*)w;
    float4 wi = w4[q8];
    float4 wj = w4[8 + q8];
    float pa = xv.x * wi.x + xv.y * wi.y + xv.z * wi.z + xv.w * wi.w;
    float pb = xv.x * wj.x + xv.y * wj.y + xv.z * wj.z + xv.w * wj.w;
    #pragma unroll
    for (int m = 4; m >= 1; m >>= 1) {
        pa += __shfl_xor(pa, m);
        pb += __shfl_xor(pb, m);
    }
    if (q8 == 0) {
        Af[node * 4 + h] = pa;
        Bf[node * 4 + h] = pb;
    }
}

// ============================================================================
// hist + rank: counters one per 64B line (shift=4); 4 edges/thread
// (r14-proven: atomic round-trips hide behind 4 independent chains here,
//  and hist has no store-throughput pressure unlike scatter)
// ============================================================================

__global__ void hist_rank_kernel(const int* __restrict__ ei,
                                 int* __restrict__ cnt,
                                 ushort* __restrict__ rank,
                                 int n_edges, int shift) {
    int base = blockIdx.x * 1024 + threadIdx.x;
    #pragma unroll
    for (int u = 0; u < 4; ++u) {
        int e = base + u * 256;
        if (e < n_edges) {
            int i = ei[e];
            int r = atomicAdd(&cnt[i << shift], 1);
            rank[e] = (ushort)r;
        }
    }
}

// ============================================================================
// scan1 (+fused scan2 via last-arriving block):
//   - block-local exclusive scan of cnt -> offs (offs[n] valid)
//   - bsums[b] = block total; LAST block scans bsums -> bscan
// Consumers fold: global_off(i) = offs[i] + bscan[i>>8]
// ============================================================================

__global__ void scan1_kernel(const int* __restrict__ cnt, int* __restrict__ offs,
                             int* __restrict__ bsums, int* __restrict__ bscan,
                             int* __restrict__ done_ctr, int n, int shift) {
    __shared__ int lds[256];
    __shared__ bool is_last;
    int i = blockIdx.x * 256 + threadIdx.x;
    int v = (i < n) ? cnt[i << shift] : 0;
    lds[threadIdx.x] = v;
    __syncthreads();
    for (int d = 1; d < 256; d <<= 1) {
        int t = (threadIdx.x >= d) ? lds[threadIdx.x - d] : 0;
        __syncthreads();
        lds[threadIdx.x] += t;
        __syncthreads();
    }
    if (i <= n) offs[i] = lds[threadIdx.x] - v;   // i==n gets local-exclusive
    if (threadIdx.x == 255) bsums[blockIdx.x] = lds[255];

    __threadfence();
    if (threadIdx.x == 0) {
        int prev = atomicAdd(done_ctr, 1);
        is_last = (prev == (int)gridDim.x - 1);
    }
    __syncthreads();
    if (is_last) {
        int nb = (int)gridDim.x;
        int bv = (threadIdx.x < nb) ? bsums[threadIdx.x] : 0;
        __syncthreads();
        lds[threadIdx.x] = bv;
        __syncthreads();
        for (int d = 1; d < 256; d <<= 1) {
            int t = (threadIdx.x >= d) ? lds[threadIdx.x - d] : 0;
            __syncthreads();
            lds[threadIdx.x] += t;
            __syncthreads();
        }
        bscan[threadIdx.x] = lds[threadIdx.x] - bv;
    }
}

// ============================================================================
// atomic-free record scatter: 2 edges/thread, 1563 blocks (~6/CU) —
// latency-bound phase needs WAVE COUNT (r7/r15 both showed 4+/thread starves)
// ============================================================================

__global__ void scatter_norank_kernel(const int* __restrict__ ei,
                                      const int* __restrict__ ej,
                                      const float* __restrict__ weights,
                                      const float4* __restrict__ A4,
                                      const float4* __restrict__ B4,
                                      const int* __restrict__ offs,
                                      const int* __restrict__ bscan,
                                      const ushort* __restrict__ rank,
                                      uint4* __restrict__ rec,
                                      int n_edges) {
    int base = blockIdx.x * (blockDim.x * 2) + threadIdx.x;
    #pragma unroll
    for (int u = 0; u < 2; ++u) {
        int e = base + u * 256;
        if (e >= n_edges) continue;
        int i = ei[e];
        int j = ej[e];
        float we = weights[e];
        int p = offs[i] + bscan[i >> 8] + (int)rank[e];
        float4 ai = A4[i];
        float4 bj = B4[j];
        float b0 = we / (1.0f + __expf(-(ai.x + bj.x)));
        float b1 = we / (1.0f + __expf(-(ai.y + bj.y)));
        float b2 = we / (1.0f + __expf(-(ai.z + bj.z)));
        float b3 = we / (1.0f + __expf(-(ai.w + bj.w)));
        uint w01 = (uint)__half_as_ushort(__float2half(b0)) |
                   ((uint)__half_as_ushort(__float2half(b1)) << 16);
        uint w23 = (uint)__half_as_ushort(__float2half(b2)) |
                   ((uint)__half_as_ushort(__float2half(b3)) << 16);
        uint4 r;
        r.x = (uint)j; r.y = w01; r.z = w23; r.w = 0u;
        rec[p] = r;
    }
}

// ============================================================================
// gather: 32 lanes/node, plain rec loads (line reuse), unroll 4, NT out store
// ============================================================================

__global__ void gather_rec_kernel(const ushort4* __restrict__ xh4,
                                  const int* __restrict__ offs,
                                  const int* __restrict__ bscan,
                                  const uint4* __restrict__ rec,
                                  float4* __restrict__ out4) {
    int gid = blockIdx.x * blockDim.x + threadIdx.x;
    int node = gid >> 5;
    int t = threadIdx.x & 31;
    int h = t >> 3;

    int start = offs[node] + bscan[node >> 8];
    int end = offs[node + 1] + bscan[(node + 1) >> 8];

    float4 acc = make_float4(0.f, 0.f, 0.f, 0.f);
    #pragma unroll 4
    for (int k = start; k < end; ++k) {
        uint4 r = rec[k];
        int j = (int)r.x;
        uint wrd = (h < 2) ? r.y : r.z;
        ushort hw = (h & 1) ? (ushort)(wrd >> 16) : (ushort)(wrd & 0xffffu);
        float beta = __half2float(__ushort_as_half(hw));
        ushort4 xv = xh4[j * 32 + t];
        acc.x += __half2float(__ushort_as_half(xv.x)) * beta;
        acc.y += __half2float(__ushort_as_half(xv.y)) * beta;
        acc.z += __half2float(__ushort_as_half(xv.z)) * beta;
        acc.w += __half2float(__ushort_as_half(xv.w)) * beta;
    }
    vfloat4 av; av.x = acc.x; av.y = acc.y; av.z = acc.z; av.w = acc.w;
    __builtin_nontemporal_store(av, (vfloat4*)&out4[node * 32 + t]);
}

// ============================================================================
// v0 ultimate fallback: atomic scatter
// ============================================================================

__global__ void node_dots_kernel(const float* __restrict__ x,
                                 const float* __restrict__ w,
                                 float* __restrict__ ab,
                                 int n_nodes) {
    int gid = blockIdx.x * blockDim.x + threadIdx.x;
    int node = gid >> 7;
    int t = threadIdx.x & 127;
    if (node >= n_nodes) return;
    int h = t >> 5;
    int c = t & 31;
    float xv = x[node * FDIM + t];
    float pa = xv * w[c];
    float pb = xv * w[OUT_CH + c];
    #pragma unroll
    for (int m = 16; m >= 1; m >>= 1) {
        pa += __shfl_xor(pa, m);
        pb += __shfl_xor(pb, m);
    }
    if (c == 0) {
        ab[node * 8 + h * 2 + 0] = pa;
        ab[node * 8 + h * 2 + 1] = pb;
    }
}

__global__ void edge_scatter_kernel(const float* __restrict__ x,
                                    const int* __restrict__ ei_arr,
                                    const int* __restrict__ ej_arr,
                                    const float* __restrict__ weights,
                                    const float* __restrict__ ab,
                                    float* __restrict__ out,
                                    int n_edges) {
    int gid = blockIdx.x * blockDim.x + threadIdx.x;
    int e = gid >> 7;
    int t = threadIdx.x & 127;
    if (e >= n_edges) return;
    int h = t >> 5;
    int i = ei_arr[e];
    int j = ej_arr[e];
    float alpha = ab[i * 8 + h * 2 + 0] + ab[j * 8 + h * 2 + 1];
    float beta = weights[e] / (1.0f + __expf(-alpha));
    atomicAdd(&out[i * FDIM + t], x[j * FDIM + t] * beta);
}

// ============================================================================

extern "C" void kernel_launch(void* const* d_in, const int* in_sizes, int n_in,
                              void* d_out, int out_size, void* d_ws, size_t ws_size,
                              hipStream_t stream) {
    const float* x       = (const float*)d_in[0];
    const int*   eidx    = (const int*)d_in[1];
    const float* weights = (const float*)d_in[2];
    const float* w       = (const float*)d_in[3];
    float* out = (float*)d_out;

    const int* ei_arr = eidx;
    const int* ej_arr = eidx + N_EDGES;

    const int NB = (N_NODES + 255) / 256;  // scan blocks (196)

    // ---- v16 workspace layout (r14 layout + bscan/done) ----
    {
        char* p = (char*)d_ws;
        ushort4* xh4  = (ushort4*)p;   p += (size_t)N_NODES * FDIM * 2;
        float*   Af   = (float*)p;     p += (size_t)N_NODES * 4 * 4;
        float*   Bf   = (float*)p;     p += (size_t)N_NODES * 4 * 4;
        uint4*   rec  = (uint4*)p;     p += (size_t)N_EDGES * 16;
        ushort*  rank = (ushort*)p;    p += (size_t)N_EDGES * 2;
        int*     offs = (int*)p;       p += (size_t)(N_NODES + 1) * 4;
        int*     bsums= (int*)p;       p += (size_t)256 * 4;
        int*     bscan= (int*)p;       p += (size_t)256 * 4;
        int*     done = (int*)p;       p += (size_t)16;
        int*     cnt  = (int*)p;       // strided counters at the end
        size_t base_need = (size_t)(p - (char*)d_ws);
        size_t need_pad  = base_need + (size_t)N_NODES * 16 * 4;  // shift=4
        size_t need_min  = base_need + (size_t)N_NODES * 4;       // shift=0

        int shift = -1;
        if (ws_size >= need_pad)      shift = 4;
        else if (ws_size >= need_min) shift = 0;

        if (shift >= 0) {
            int n_cnt4 = (N_NODES << shift) / 4;
            prep_kernel<<<(N_NODES * 32) / 256, 256, 0, stream>>>(
                (const float4*)x, w, Af, Bf, xh4, (int4*)cnt, n_cnt4, done);
            hist_rank_kernel<<<(N_EDGES + 1023) / 1024, 256, 0, stream>>>(
                ei_arr, cnt, rank, N_EDGES, shift);
            scan1_kernel<<<NB, 256, 0, stream>>>(
                cnt, offs, bsums, bscan, done, N_NODES, shift);
            scatter_norank_kernel<<<(N_EDGES + 511) / 512, 256, 0, stream>>>(
                ei_arr, ej_arr, weights, (const float4*)Af, (const float4*)Bf,
                offs, bscan, rank, rec, N_EDGES);
            gather_rec_kernel<<<(N_NODES * 32) / 256, 256, 0, stream>>>(
                xh4, offs, bscan, rec, (float4*)out);
            return;
        }
    }

    // ---- v0 atomic fallback ----
    {
        float* ab = (float*)d_ws;  // 1.6MB
        int grid = (N_NODES * FDIM + 255) / 256;
        node_dots_kernel<<<grid, 256, 0, stream>>>(x, w, ab, N_NODES);
        hipMemsetAsync(d_out, 0, (size_t)out_size * sizeof(float), stream);
        long long threads_total = (long long)N_EDGES * FDIM;
        long long g = (threads_total + 255) / 256;
        edge_scatter_kernel<<<(int)g, 256, 0, stream>>>(
            x, ei_arr, ej_arr, weights, ab, out, N_EDGES);
    }
}

// Round 17
// 107.030 us; speedup vs baseline: 1.1510x; 1.1052x over previous
//
#include <hip/hip_runtime.h>
#include <hip/hip_bf16.h>
#include <hip/hip_fp16.h>

#define N_NODES 50000
#define N_EDGES 800000
#define HEADS 4
#define OUT_CH 32
#define FDIM (HEADS * OUT_CH)   // 128

typedef float vfloat4 __attribute__((ext_vector_type(4)));

// ============================================================================
// prep: A/B node dots + fp16 x-table + zero the strided counters
// ============================================================================

__global__ void prep_kernel(const float4* __restrict__ x4,
                            const float* __restrict__ w,
                            float* __restrict__ Af,
                            float* __restrict__ Bf,
                            ushort4* __restrict__ xh4,
                            int4* __restrict__ cnt_zero,
                            int n_cnt4) {
    int gid = blockIdx.x * blockDim.x + threadIdx.x;

    if (gid < n_cnt4) cnt_zero[gid] = make_int4(0, 0, 0, 0);

    int node = gid >> 5;
    int t = threadIdx.x & 31;
    int h = t >> 3;
    int q8 = t & 7;

    float4 xv = x4[node * 32 + t];

    ushort4 u;
    u.x = __half_as_ushort(__float2half(xv.x));
    u.y = __half_as_ushort(__float2half(xv.y));
    u.z = __half_as_ushort(__float2half(xv.z));
    u.w = __half_as_ushort(__float2half(xv.w));
    xh4[node * 32 + t] = u;

    const float4* w4 = (const float4*)w;
    float4 wi = w4[q8];
    float4 wj = w4[8 + q8];
    float pa = xv.x * wi.x + xv.y * wi.y + xv.z * wi.z + xv.w * wi.w;
    float pb = xv.x * wj.x + xv.y * wj.y + xv.z * wj.z + xv.w * wj.w;
    #pragma unroll
    for (int m = 4; m >= 1; m >>= 1) {
        pa += __shfl_xor(pa, m);
        pb += __shfl_xor(pb, m);
    }
    if (q8 == 0) {
        Af[node * 4 + h] = pa;
        Bf[node * 4 + h] = pb;
    }
}

// ============================================================================
// hist + rank: counters one per 64B line (shift=4); 4 edges/thread for
// atomic MLP (782 blocks — still ~3 blocks/CU, no starvation)
// ============================================================================

__global__ void hist_rank_kernel(const int* __restrict__ ei,
                                 int* __restrict__ cnt,
                                 ushort* __restrict__ rank,
                                 int n_edges, int shift) {
    int base = blockIdx.x * 1024 + threadIdx.x;
    #pragma unroll
    for (int u = 0; u < 4; ++u) {
        int e = base + u * 256;
        if (e < n_edges) {
            int i = ei[e];
            int r = atomicAdd(&cnt[i << shift], 1);
            rank[e] = (ushort)r;
        }
    }
}

// ============================================================================
// scan: block-local exclusive scan (writes i<=n so offs[n] is valid) + bsums;
// consumers fold the block offset: off(i) = offs[i] + bsums[i>>8]
// (separate scan2 launch — the fused last-block __threadfence pattern
//  measured +11us on r16: device-scope fences are expensive on CDNA4)
// ============================================================================

__global__ void scan1_kernel(const int* __restrict__ cnt, int* __restrict__ offs,
                             int* __restrict__ bsums, int n, int shift) {
    __shared__ int lds[256];
    int i = blockIdx.x * 256 + threadIdx.x;
    int v = (i < n) ? cnt[i << shift] : 0;
    lds[threadIdx.x] = v;
    __syncthreads();
    for (int d = 1; d < 256; d <<= 1) {
        int t = (threadIdx.x >= d) ? lds[threadIdx.x - d] : 0;
        __syncthreads();
        lds[threadIdx.x] += t;
        __syncthreads();
    }
    if (i <= n) offs[i] = lds[threadIdx.x] - v;   // i==n gets local-exclusive
    if (threadIdx.x == 255) bsums[blockIdx.x] = lds[255];
}

__global__ void scan2_kernel(int* __restrict__ bsums, int nb) {
    __shared__ int lds[256];
    int v = (threadIdx.x < nb) ? bsums[threadIdx.x] : 0;
    lds[threadIdx.x] = v;
    __syncthreads();
    for (int d = 1; d < 256; d <<= 1) {
        int t = (threadIdx.x >= d) ? lds[threadIdx.x - d] : 0;
        __syncthreads();
        lds[threadIdx.x] += t;
        __syncthreads();
    }
    if (threadIdx.x < nb) bsums[threadIdx.x] = lds[threadIdx.x] - v;
}

// ============================================================================
// atomic-free record scatter: 2 edges/thread, 1563 blocks (~6/CU) —
// latency-bound scatter needs WAVE COUNT (r7/r15: 4+/thread starves)
// ============================================================================

__global__ void scatter_norank_kernel(const int* __restrict__ ei,
                                      const int* __restrict__ ej,
                                      const float* __restrict__ weights,
                                      const float4* __restrict__ A4,
                                      const float4* __restrict__ B4,
                                      const int* __restrict__ offs,
                                      const int* __restrict__ bsums,
                                      const ushort* __restrict__ rank,
                                      uint4* __restrict__ rec,
                                      int n_edges) {
    int base = blockIdx.x * (blockDim.x * 2) + threadIdx.x;
    #pragma unroll
    for (int u = 0; u < 2; ++u) {
        int e = base + u * 256;
        if (e >= n_edges) continue;
        int i = ei[e];
        int j = ej[e];
        float we = weights[e];
        int p = offs[i] + bsums[i >> 8] + (int)rank[e];
        float4 ai = A4[i];
        float4 bj = B4[j];
        float b0 = we / (1.0f + __expf(-(ai.x + bj.x)));
        float b1 = we / (1.0f + __expf(-(ai.y + bj.y)));
        float b2 = we / (1.0f + __expf(-(ai.z + bj.z)));
        float b3 = we / (1.0f + __expf(-(ai.w + bj.w)));
        uint w01 = (uint)__half_as_ushort(__float2half(b0)) |
                   ((uint)__half_as_ushort(__float2half(b1)) << 16);
        uint w23 = (uint)__half_as_ushort(__float2half(b2)) |
                   ((uint)__half_as_ushort(__float2half(b3)) << 16);
        uint4 r;
        r.x = (uint)j; r.y = w01; r.z = w23; r.w = 0u;
        rec[p] = r;
    }
}

// ============================================================================
// gather: 32 lanes/node, PLAIN rec loads (4 recs/64B line reuse), unroll 4,
// NT store only on out
// ============================================================================

__global__ void gather_rec_kernel(const ushort4* __restrict__ xh4,
                                  const int* __restrict__ offs,
                                  const int* __restrict__ bsums,
                                  const uint4* __restrict__ rec,
                                  float4* __restrict__ out4) {
    int gid = blockIdx.x * blockDim.x + threadIdx.x;
    int node = gid >> 5;
    int t = threadIdx.x & 31;
    int h = t >> 3;

    int start = offs[node] + bsums[node >> 8];
    int end = offs[node + 1] + bsums[(node + 1) >> 8];

    float4 acc = make_float4(0.f, 0.f, 0.f, 0.f);
    #pragma unroll 4
    for (int k = start; k < end; ++k) {
        uint4 r = rec[k];
        int j = (int)r.x;
        uint wrd = (h < 2) ? r.y : r.z;
        ushort hw = (h & 1) ? (ushort)(wrd >> 16) : (ushort)(wrd & 0xffffu);
        float beta = __half2float(__ushort_as_half(hw));
        ushort4 xv = xh4[j * 32 + t];
        acc.x += __half2float(__ushort_as_half(xv.x)) * beta;
        acc.y += __half2float(__ushort_as_half(xv.y)) * beta;
        acc.z += __half2float(__ushort_as_half(xv.z)) * beta;
        acc.w += __half2float(__ushort_as_half(xv.w)) * beta;
    }
    vfloat4 av; av.x = acc.x; av.y = acc.y; av.z = acc.z; av.w = acc.w;
    __builtin_nontemporal_store(av, (vfloat4*)&out4[node * 32 + t]);
}

// ============================================================================
// v0 ultimate fallback: atomic scatter
// ============================================================================

__global__ void node_dots_kernel(const float* __restrict__ x,
                                 const float* __restrict__ w,
                                 float* __restrict__ ab,
                                 int n_nodes) {
    int gid = blockIdx.x * blockDim.x + threadIdx.x;
    int node = gid >> 7;
    int t = threadIdx.x & 127;
    if (node >= n_nodes) return;
    int h = t >> 5;
    int c = t & 31;
    float xv = x[node * FDIM + t];
    float pa = xv * w[c];
    float pb = xv * w[OUT_CH + c];
    #pragma unroll
    for (int m = 16; m >= 1; m >>= 1) {
        pa += __shfl_xor(pa, m);
        pb += __shfl_xor(pb, m);
    }
    if (c == 0) {
        ab[node * 8 + h * 2 + 0] = pa;
        ab[node * 8 + h * 2 + 1] = pb;
    }
}

__global__ void edge_scatter_kernel(const float* __restrict__ x,
                                    const int* __restrict__ ei_arr,
                                    const int* __restrict__ ej_arr,
                                    const float* __restrict__ weights,
                                    const float* __restrict__ ab,
                                    float* __restrict__ out,
                                    int n_edges) {
    int gid = blockIdx.x * blockDim.x + threadIdx.x;
    int e = gid >> 7;
    int t = threadIdx.x & 127;
    if (e >= n_edges) return;
    int h = t >> 5;
    int i = ei_arr[e];
    int j = ej_arr[e];
    float alpha = ab[i * 8 + h * 2 + 0] + ab[j * 8 + h * 2 + 1];
    float beta = weights[e] / (1.0f + __expf(-alpha));
    atomicAdd(&out[i * FDIM + t], x[j * FDIM + t] * beta);
}

// ============================================================================

extern "C" void kernel_launch(void* const* d_in, const int* in_sizes, int n_in,
                              void* d_out, int out_size, void* d_ws, size_t ws_size,
                              hipStream_t stream) {
    const float* x       = (const float*)d_in[0];
    const int*   eidx    = (const int*)d_in[1];
    const float* weights = (const float*)d_in[2];
    const float* w       = (const float*)d_in[3];
    float* out = (float*)d_out;

    const int* ei_arr = eidx;
    const int* ej_arr = eidx + N_EDGES;

    const int NB = (N_NODES + 255) / 256;  // scan blocks (196)

    // ---- v17 = r14 layout (measured 107.3us champion) ----
    // xh: 12.8MB | A: .8MB | B: .8MB | rec: 12.8MB | rank: 1.6MB |
    // offs: (N+1)*4 | bsums: 1KB | cnt_pad: N*stride*4
    {
        char* p = (char*)d_ws;
        ushort4* xh4  = (ushort4*)p;   p += (size_t)N_NODES * FDIM * 2;
        float*   Af   = (float*)p;     p += (size_t)N_NODES * 4 * 4;
        float*   Bf   = (float*)p;     p += (size_t)N_NODES * 4 * 4;
        uint4*   rec  = (uint4*)p;     p += (size_t)N_EDGES * 16;
        ushort*  rank = (ushort*)p;    p += (size_t)N_EDGES * 2;
        int*     offs = (int*)p;       p += (size_t)(N_NODES + 1) * 4;
        int*     bsums= (int*)p;       p += (size_t)256 * 4;
        int*     cnt  = (int*)p;       // strided counters at the end
        size_t base_need = (size_t)(p - (char*)d_ws);
        size_t need_pad  = base_need + (size_t)N_NODES * 16 * 4;  // shift=4
        size_t need_min  = base_need + (size_t)N_NODES * 4;       // shift=0

        int shift = -1;
        if (ws_size >= need_pad)      shift = 4;
        else if (ws_size >= need_min) shift = 0;

        if (shift >= 0) {
            int n_cnt4 = (N_NODES << shift) / 4;
            prep_kernel<<<(N_NODES * 32) / 256, 256, 0, stream>>>(
                (const float4*)x, w, Af, Bf, xh4, (int4*)cnt, n_cnt4);
            hist_rank_kernel<<<(N_EDGES + 1023) / 1024, 256, 0, stream>>>(
                ei_arr, cnt, rank, N_EDGES, shift);
            scan1_kernel<<<NB, 256, 0, stream>>>(cnt, offs, bsums, N_NODES, shift);
            scan2_kernel<<<1, 256, 0, stream>>>(bsums, NB);
            scatter_norank_kernel<<<(N_EDGES + 511) / 512, 256, 0, stream>>>(
                ei_arr, ej_arr, weights, (const float4*)Af, (const float4*)Bf,
                offs, bsums, rank, rec, N_EDGES);
            gather_rec_kernel<<<(N_NODES * 32) / 256, 256, 0, stream>>>(
                xh4, offs, bsums, rec, (float4*)out);
            return;
        }
    }

    // ---- v0 atomic fallback ----
    {
        float* ab = (float*)d_ws;  // 1.6MB
        int grid = (N_NODES * FDIM + 255) / 256;
        node_dots_kernel<<<grid, 256, 0, stream>>>(x, w, ab, N_NODES);
        hipMemsetAsync(d_out, 0, (size_t)out_size * sizeof(float), stream);
        long long threads_total = (long long)N_EDGES * FDIM;
        long long g = (threads_total + 255) / 256;
        edge_scatter_kernel<<<(int)g, 256, 0, stream>>>(
            x, ei_arr, ej_arr, weights, ab, out, N_EDGES);
    }
}